// Round 14
// baseline (286.005 us; speedup 1.0000x reference)
//
#include <hip/hip_runtime.h>
#include <math.h>
#include <stdint.h>
#include <stddef.h>

#define N_NODES 8192
#define N_EDGES 524288
#define N_PAIRS 262144
#define N_TYPES 86
#define F1 128
#define F2 64

typedef unsigned short ushort_t;
typedef unsigned int uint_t;
typedef __attribute__((ext_vector_type(8))) short bfrag;
typedef __attribute__((ext_vector_type(4))) float ffrag;

typedef __attribute__((address_space(3))) char lds_char;
typedef __attribute__((address_space(1))) const char g_char;

__device__ __forceinline__ void gload16(const void* g, void* l) {
  __builtin_amdgcn_global_load_lds((const g_char*)g, (lds_char*)l, 16, 0, 0);
}

__device__ inline ushort_t f2bf(float f) {
  uint_t u = __float_as_uint(f);
  uint_t r = u + 0x7fffu + ((u >> 16) & 1u);
  return (ushort_t)(r >> 16);
}
__device__ inline float bf2f(ushort_t h) {
  return __uint_as_float(((uint_t)h) << 16);
}

// ---------------- degree / CSR build ----------------

__global__ void zero_k(int* __restrict__ p) {
  p[blockIdx.x * 256 + threadIdx.x] = 0;
}

__global__ void count_deg_k(const int* __restrict__ dst, int* __restrict__ cnt) {
  int e = blockIdx.x * blockDim.x + threadIdx.x;
  if (e < N_EDGES) atomicAdd(&cnt[dst[e]], 1);
}

__global__ void scan_k(const int* __restrict__ cnt, int* __restrict__ rp,
                       int* __restrict__ fill, float* __restrict__ dinv) {
  __shared__ int s[1024];
  int t = threadIdx.x;
  int v[8];
  int sum = 0;
#pragma unroll
  for (int i = 0; i < 8; i++) {
    v[i] = cnt[t * 8 + i];
    dinv[t * 8 + i] = 1.0f / sqrtf((float)(v[i] + 1));
    sum += v[i];
  }
  s[t] = sum;
  __syncthreads();
  for (int off = 1; off < 1024; off <<= 1) {
    int add = (t >= off) ? s[t - off] : 0;
    __syncthreads();
    s[t] += add;
    __syncthreads();
  }
  int excl = s[t] - sum;
#pragma unroll
  for (int i = 0; i < 8; i++) {
    rp[t * 8 + i] = excl;
    fill[t * 8 + i] = excl;
    excl += v[i];
  }
  if (t == 1023) rp[N_NODES] = excl;
}

__global__ void scatter_k(const int* __restrict__ src, const int* __restrict__ dst,
                          int* fill, int* __restrict__ csr) {
  int e = blockIdx.x * blockDim.x + threadIdx.x;
  if (e < N_EDGES) {
    int d = dst[e];
    int pos = atomicAdd(&fill[d], 1);
    csr[pos] = src[e];
  }
}

// ---------------- W1 split + transpose: W1th/W1tl[n][k] = hi/lo(W1[k][n]) ----------------

__global__ __launch_bounds__(256) void w1split_k(const float* __restrict__ W1,
                                                 ushort_t* __restrict__ W1th,
                                                 ushort_t* __restrict__ W1tl) {
  __shared__ ushort_t lh[32 * 65];
  __shared__ ushort_t ll[32 * 65];
  int tid = threadIdx.x;
  int k0 = blockIdx.x * 64;
  int n0 = blockIdx.y * 32;
#pragma unroll
  for (int i = 0; i < 8; i++) {
    int c = tid + 256 * i;
    int kr = c >> 5, nc = c & 31;
    float v = W1[(size_t)(k0 + kr) * F1 + n0 + nc];
    ushort_t h = f2bf(v);
    ushort_t l = f2bf(v - bf2f(h));
    lh[nc * 65 + kr] = h;
    ll[nc * 65 + kr] = l;
  }
  __syncthreads();
#pragma unroll
  for (int i = 0; i < 2; i++) {
    int c = tid + 256 * i;
    int buf = c >> 8;
    int cc = c & 255;
    int nr = cc >> 3, kc = cc & 7;
    const ushort_t* l = buf ? ll : lh;
    uint4 u;
    u.x = (uint_t)l[nr * 65 + kc * 8 + 0] | ((uint_t)l[nr * 65 + kc * 8 + 1] << 16);
    u.y = (uint_t)l[nr * 65 + kc * 8 + 2] | ((uint_t)l[nr * 65 + kc * 8 + 3] << 16);
    u.z = (uint_t)l[nr * 65 + kc * 8 + 4] | ((uint_t)l[nr * 65 + kc * 8 + 5] << 16);
    u.w = (uint_t)l[nr * 65 + kc * 8 + 6] | ((uint_t)l[nr * 65 + kc * 8 + 7] << 16);
    ushort_t* dst = (buf ? W1tl : W1th) + (size_t)(n0 + nr) * N_NODES + k0 + kc * 8;
    *(uint4*)dst = u;
  }
}

// ---------------- GEMM1: page-batched K-groups (128k), counted vmcnt ----------------
// 256 thr (4 waves, all share M=32, each 32 N-cols), BK=32, group = 4 steps.
// A: per group, thread issues 4 back-to-back float4s (512B/row clustered) ONE
//    GROUP AHEAD; converted to split-bf16 and ds_written once per group.
// B: quad-buffered 4x16KB via global_load_lds (R13 mapping verbatim).
// vmcnt drains to 0 only once per 4 steps; 1 barrier per step + 1 per group.
// LDS: A(H8K,L8K) + B 64K = 80KB -> 2 blocks/CU.

#define ALDS_H 0
#define ALDS_L 8192
#define BLDS(j) (16384 + ((j) & 3) * 16384)

#define SCHED0 __builtin_amdgcn_sched_barrier(0)
#define WAITVM(N)  do { asm volatile("s_waitcnt vmcnt(" #N ")" ::: "memory"); SCHED0; } while (0)
#define WAITLG     do { asm volatile("s_waitcnt lgkmcnt(0)" ::: "memory"); SCHED0; } while (0)

__global__ __launch_bounds__(256, 2) void gemm1_mfma_k(const float* __restrict__ x,
                                                       const ushort_t* __restrict__ W1th,
                                                       const ushort_t* __restrict__ W1tl,
                                                       float* __restrict__ part, int kspan) {
  __shared__ __align__(16) char lds[81920];
  int tid = threadIdx.x;
  int wave = tid >> 6, lane = tid & 63;
  int lrow = lane & 15, kgrp = lane >> 4;
  int m_blk = blockIdx.y * 32;
  int kbase = blockIdx.x * kspan;
  int ngroups = kspan >> 7;  // 128 k per group
  int gmask = ngroups - 1;
  int g0 = (5 * blockIdx.y + 3 * blockIdx.x) & gmask;  // rotation (R13-proven)

  // A coords: thread covers row (tid>>3), floats (tid&7)*16 .. +15 of the window
  int ar = tid >> 3, ac = tid & 7;
  const float* abase = x + (size_t)(m_blk + ar) * N_NODES + ac * 16;

  // B gload mapping (R13 verbatim)
  int bq = wave;
  int b_row = bq * 32 + (lane >> 2);
  int b_kel = ((lane & 3) ^ ((lane >> 2) & 3)) << 3;

  ffrag acc[2][2];
#pragma unroll
  for (int mi = 0; mi < 2; mi++)
#pragma unroll
    for (int ni = 0; ni < 2; ni++) acc[mi][ni] = (ffrag)(0.0f);

  float4 av[4];

#define ISSUE_A(WG)                                                                  \
  {                                                                                  \
    const float* p_ = abase + (size_t)(kbase + (WG) * 128);                          \
    av[0] = *(const float4*)(p_ + 0);                                                \
    av[1] = *(const float4*)(p_ + 4);                                                \
    av[2] = *(const float4*)(p_ + 8);                                                \
    av[3] = *(const float4*)(p_ + 12);                                               \
  }

#define ISSUE_B(K0, J)                                                               \
  {                                                                                  \
    _Pragma("unroll") for (int i = 0; i < 2; i++) {                                  \
      const ushort_t* gh = W1th + (size_t)(b_row + i * 16) * N_NODES + (K0) + b_kel; \
      gload16(gh, lds + BLDS(J) + bq * 2048 + i * 1024);                             \
      const ushort_t* gl = W1tl + (size_t)(b_row + i * 16) * N_NODES + (K0) + b_kel; \
      gload16(gl, lds + BLDS(J) + 8192 + bq * 2048 + i * 1024);                      \
    }                                                                                \
  }

#define PACKH(a, b) make_uint4(                                                      \
    (uint_t)f2bf(a.x) | ((uint_t)f2bf(a.y) << 16),                                   \
    (uint_t)f2bf(a.z) | ((uint_t)f2bf(a.w) << 16),                                   \
    (uint_t)f2bf(b.x) | ((uint_t)f2bf(b.y) << 16),                                   \
    (uint_t)f2bf(b.z) | ((uint_t)f2bf(b.w) << 16))

#define PACKL(a, b) make_uint4(                                                      \
    (uint_t)f2bf(a.x - bf2f(f2bf(a.x))) | ((uint_t)f2bf(a.y - bf2f(f2bf(a.y))) << 16), \
    (uint_t)f2bf(a.z - bf2f(f2bf(a.z))) | ((uint_t)f2bf(a.w - bf2f(f2bf(a.w))) << 16), \
    (uint_t)f2bf(b.x - bf2f(f2bf(b.x))) | ((uint_t)f2bf(b.y - bf2f(f2bf(b.y))) << 16), \
    (uint_t)f2bf(b.z - bf2f(f2bf(b.z))) | ((uint_t)f2bf(b.w - bf2f(f2bf(b.w))) << 16))

#define STOREA()                                                                     \
  {                                                                                  \
    uint_t o0 = ar * 256 + ((((ac * 2) ^ (ar & 15))) << 4);                          \
    uint_t o1 = ar * 256 + ((((ac * 2 + 1) ^ (ar & 15))) << 4);                      \
    *(uint4*)(lds + ALDS_H + o0) = PACKH(av[0], av[1]);                              \
    *(uint4*)(lds + ALDS_H + o1) = PACKH(av[2], av[3]);                              \
    *(uint4*)(lds + ALDS_L + o0) = PACKL(av[0], av[1]);                              \
    *(uint4*)(lds + ALDS_L + o1) = PACKL(av[2], av[3]);                              \
  }

#define COMPUTE(J)                                                                   \
  {                                                                                  \
    bfrag bh[2], bl[2];                                                              \
    _Pragma("unroll") for (int ni = 0; ni < 2; ni++) {                               \
      int brow = wave * 32 + ni * 16 + lrow;                                         \
      uint_t boff = brow * 64 + ((kgrp * 16) ^ ((brow & 3) << 4));                   \
      bh[ni] = *(const bfrag*)(lds + BLDS(J) + boff);                                \
      bl[ni] = *(const bfrag*)(lds + BLDS(J) + 8192 + boff);                         \
    }                                                                                \
    _Pragma("unroll") for (int mi = 0; mi < 2; mi++) {                               \
      int arw = mi * 16 + lrow;                                                      \
      uint_t aoff = arw * 256 + (((((J) * 4 + kgrp) ^ (arw & 15))) << 4);            \
      bfrag ah = *(const bfrag*)(lds + ALDS_H + aoff);                               \
      bfrag al = *(const bfrag*)(lds + ALDS_L + aoff);                               \
      _Pragma("unroll") for (int ni = 0; ni < 2; ni++) {                             \
        acc[mi][ni] = __builtin_amdgcn_mfma_f32_16x16x32_bf16(ah, bh[ni], acc[mi][ni], 0, 0, 0); \
        acc[mi][ni] = __builtin_amdgcn_mfma_f32_16x16x32_bf16(ah, bl[ni], acc[mi][ni], 0, 0, 0); \
        acc[mi][ni] = __builtin_amdgcn_mfma_f32_16x16x32_bf16(al, bh[ni], acc[mi][ni], 0, 0, 0); \
      }                                                                              \
    }                                                                                \
  }

  // k-offset of group wg, step j
#define KB(WG, J) (kbase + (WG) * 128 + (J) * 32)

  // -------- prologue: B(g0.0) + A(g0) --------
  {
    int wg = g0;
    ISSUE_B(KB(wg, 0), 0);
    SCHED0;
    ISSUE_A(wg);
    SCHED0;
    WAITVM(0);
    STOREA();
    int wgn = (g0 + 1) & gmask;
    ISSUE_B(KB(wg, 1), 1);
    ISSUE_B(KB(wg, 2), 2);
    ISSUE_B(KB(wg, 3), 3);
    SCHED0;
    ISSUE_A(wgn);
    SCHED0;
    WAITLG;
    __builtin_amdgcn_s_barrier();
    SCHED0;
  }

  // -------- main loop over groups --------
  // entry invariant: A-LDS = group (g0+g); buf0..3 staged/in-flight per ledger;
  // outstanding vm = B.1(4) + B.2(4) + B.3(4) + av(next group)(4) = 16
  for (int g = 0; g < ngroups; ++g) {
    int wgn = (g0 + g + 1) & gmask;
    // j=0
    __builtin_amdgcn_s_setprio(1);
    COMPUTE(0);
    __builtin_amdgcn_s_setprio(0);
    WAITVM(12);                    // drain B.1 (oldest); keep B.2,B.3,av
    __builtin_amdgcn_s_barrier();  // buf1 ready for all
    SCHED0;
    ISSUE_B(KB(wgn, 0), 0);        // buf0 free (all read it in j=0) -> outstanding 16
    SCHED0;
    // j=1
    __builtin_amdgcn_s_setprio(1);
    COMPUTE(1);
    __builtin_amdgcn_s_setprio(0);
    WAITVM(12);                    // drain B.2; keep B.3, av, Bn.0
    __builtin_amdgcn_s_barrier();
    SCHED0;
    // j=2
    __builtin_amdgcn_s_setprio(1);
    COMPUTE(2);
    __builtin_amdgcn_s_setprio(0);
    WAITVM(8);                     // drain B.3; keep av, Bn.0
    __builtin_amdgcn_s_barrier();
    SCHED0;
    // j=3
    __builtin_amdgcn_s_setprio(1);
    COMPUTE(3);
    __builtin_amdgcn_s_setprio(0);
    __builtin_amdgcn_s_barrier();  // all waves done with A-LDS + buf3
    SCHED0;
    if (g + 1 < ngroups) {
      WAITVM(0);                   // av (next group) + Bn.0 landed
      STOREA();                    // rewrite A-LDS for group wgn
      ISSUE_B(KB(wgn, 1), 1);
      ISSUE_B(KB(wgn, 2), 2);
      ISSUE_B(KB(wgn, 3), 3);
      SCHED0;
      ISSUE_A((g0 + g + 2) & gmask);
      SCHED0;
      WAITLG;
      __builtin_amdgcn_s_barrier();
      SCHED0;
    }
  }

  // -------- epilogue: C[row=(lane>>4)*4+r][col=lane&15] per 16x16 frag --------
  float* outp = part + (size_t)blockIdx.x * (N_NODES * F1);
#pragma unroll
  for (int mi = 0; mi < 2; mi++) {
#pragma unroll
    for (int ni = 0; ni < 2; ni++) {
      int col = wave * 32 + ni * 16 + lrow;
#pragma unroll
      for (int r = 0; r < 4; r++) {
        int row = m_blk + mi * 16 + kgrp * 4 + r;
        outp[(size_t)row * F1 + col] = acc[mi][ni][r];
      }
    }
  }
#undef ISSUE_A
#undef ISSUE_B
#undef STOREA
#undef COMPUTE
#undef KB
#undef PACKH
#undef PACKL
}

// in-place safe: each thread reads all S parts at its index, then writes part[0].
__global__ void reduceS_k(const float* __restrict__ part, float* __restrict__ xw1, int S) {
  int i = blockIdx.x * blockDim.x + threadIdx.x;
  float4 a = ((const float4*)part)[i];
  for (int s = 1; s < S; s++) {
    float4 b = ((const float4*)(part + (size_t)s * N_NODES * F1))[i];
    a.x += b.x; a.y += b.y; a.z += b.z; a.w += b.w;
  }
  ((float4*)xw1)[i] = a;
}

// ---------------- aggregation (gather over CSR) + bias + relu ----------------

template <int F>
__global__ void agg_k(const float* __restrict__ xw, const int* __restrict__ csr,
                      const int* __restrict__ rp, const float* __restrict__ dinv,
                      const float* __restrict__ bias, float* __restrict__ hout) {
  int node = blockIdx.x;
  int f = threadIdx.x;
  __shared__ int sidx[F];
  __shared__ float sdv[F];
  int beg = rp[node], end = rp[node + 1];
  float acc = 0.f;
  for (int base = beg; base < end; base += F) {
    int n = end - base;
    if (n > F) n = F;
    __syncthreads();
    if (f < n) {
      int s = csr[base + f];
      sidx[f] = s;
      sdv[f] = dinv[s];
    }
    __syncthreads();
    for (int i = 0; i < n; i++) acc += xw[(size_t)sidx[i] * F + f] * sdv[i];
  }
  float dv = dinv[node];
  float v = (acc + xw[(size_t)node * F + f] * dv) * dv + bias[f];
  hout[(size_t)node * F + f] = v > 0.f ? v : 0.f;
}

// ---------------- GEMM2: h1[8192,128] @ W2[128,64] ----------------

__global__ __launch_bounds__(256) void gemm2_k(const float* __restrict__ h1,
                                               const float* __restrict__ W2,
                                               float* __restrict__ xw2) {
  __shared__ float W2s[F1 * F2];
  __shared__ float As[16 * F1];
  int tid = threadIdx.x;
  int r0 = blockIdx.x * 16;
#pragma unroll
  for (int j = 0; j < 8; j++)
    ((float4*)W2s)[tid + 256 * j] = ((const float4*)W2)[tid + 256 * j];
#pragma unroll
  for (int j = 0; j < 2; j++)
    ((float4*)As)[tid + 256 * j] = ((const float4*)(h1 + (size_t)r0 * F1))[tid + 256 * j];
  __syncthreads();
  int r = tid >> 4, c4 = tid & 15;
  float4 acc = make_float4(0.f, 0.f, 0.f, 0.f);
#pragma unroll 8
  for (int k = 0; k < F1; k++) {
    float a = As[r * F1 + k];
    float4 bv = *(float4*)&W2s[k * F2 + 4 * c4];
    acc.x += a * bv.x; acc.y += a * bv.y; acc.z += a * bv.z; acc.w += a * bv.w;
  }
  *(float4*)&xw2[(size_t)(r0 + r) * F2 + 4 * c4] = acc;
}

// ---------------- P tables: P[i][0:86]=h2[i]@Wfc[:64], P[i][86:172]=h2[i]@Wfc[64:] ----------------

__global__ void pboth_k(const float* __restrict__ h2, const float* __restrict__ Wfc,
                        float* __restrict__ P) {
  __shared__ float hs[64 * 16];
  int tid = threadIdx.x;  // 192
  int r0 = blockIdx.x * 16;
  for (int idx = tid; idx < 256; idx += 192) {
    int row = idx >> 4, k4 = idx & 15;
    float4 h = *(const float4*)&h2[(size_t)(r0 + row) * F2 + 4 * k4];
    hs[(4 * k4 + 0) * 16 + row] = h.x;
    hs[(4 * k4 + 1) * 16 + row] = h.y;
    hs[(4 * k4 + 2) * 16 + row] = h.z;
    hs[(4 * k4 + 3) * 16 + row] = h.w;
  }
  __syncthreads();
  if (tid < 172) {
    int half = tid < 86 ? 0 : 1;
    int j = tid - 86 * half;
    const float* wp = Wfc + (size_t)(64 * half) * N_TYPES + j;
    float acc[16];
#pragma unroll
    for (int r = 0; r < 16; r++) acc[r] = 0.f;
    for (int k = 0; k < 64; k++) {
      float w = wp[(size_t)k * N_TYPES];
      const float* hk = &hs[k * 16];
#pragma unroll
      for (int r = 0; r < 16; r++) acc[r] += hk[r] * w;
    }
#pragma unroll
    for (int r = 0; r < 16; r++) P[(size_t)(r0 + r) * 172 + tid] = acc[r];
  }
}

// ---------------- final: out[p][t] = sigmoid(P1[d1[p]][t] + P2[d2[p]][t] + bfc[t]) ----------------

__global__ void final_k(const float* __restrict__ P, const int* __restrict__ d1,
                        const int* __restrict__ d2, const float* __restrict__ bfc,
                        float* __restrict__ out) {
  int gid = blockIdx.x * blockDim.x + threadIdx.x;
  if (gid >= N_PAIRS * 43) return;
  int p = gid / 43;
  int j = gid - p * 43;
  int a = d1[p], b = d2[p];
  float2 v1 = *(const float2*)&P[(size_t)a * 172 + 2 * j];
  float2 v2 = *(const float2*)&P[(size_t)b * 172 + 86 + 2 * j];
  float2 bb = *(const float2*)&bfc[2 * j];
  float z0 = v1.x + v2.x + bb.x;
  float z1 = v1.y + v2.y + bb.y;
  float2 o;
  o.x = 1.0f / (1.0f + expf(-z0));
  o.y = 1.0f / (1.0f + expf(-z1));
  *(float2*)&out[(size_t)p * 86 + 2 * j] = o;
}

// ---------------- launch ----------------

extern "C" void kernel_launch(void* const* d_in, const int* in_sizes, int n_in,
                              void* d_out, int out_size, void* d_ws, size_t ws_size,
                              hipStream_t stream) {
  const float* x   = (const float*)d_in[0];
  const int*   ei  = (const int*)d_in[1];
  const int*   d1  = (const int*)d_in[2];
  const int*   d2  = (const int*)d_in[3];
  const float* W1  = (const float*)d_in[4];
  const float* b1  = (const float*)d_in[5];
  const float* W2  = (const float*)d_in[6];
  const float* b2  = (const float*)d_in[7];
  const float* Wfc = (const float*)d_in[8];
  const float* bfc = (const float*)d_in[9];
  float* out = (float*)d_out;

  const int* esrc = ei;
  const int* edst = ei + N_EDGES;

  char* w = (char*)d_ws;
  size_t off = 0;
  auto alloc = [&](size_t bytes) -> char* {
    char* p = w + off;
    off += (bytes + 255) & ~(size_t)255;
    return p;
  };
  int*      cnt  = (int*)alloc((size_t)N_NODES * 4);
  float*    dinv = (float*)alloc((size_t)N_NODES * 4);
  int*      rp   = (int*)alloc((size_t)(N_NODES + 1) * 4);
  int*      fill = (int*)alloc((size_t)N_NODES * 4);
  int*      csr  = (int*)alloc((size_t)N_EDGES * 4);
  ushort_t* W1th = (ushort_t*)alloc((size_t)N_NODES * F1 * 2);
  ushort_t* W1tl = (ushort_t*)alloc((size_t)N_NODES * F1 * 2);
  float*    h1   = (float*)alloc((size_t)N_NODES * F1 * 4);
  float*    xw2  = (float*)alloc((size_t)N_NODES * F2 * 4);
  float*    h2   = (float*)alloc((size_t)N_NODES * F2 * 4);
  float*    P    = (float*)alloc((size_t)N_NODES * 172 * 4);

  size_t partBytes = (size_t)N_NODES * F1 * 4;  // 4MB per split
  int S = 8;
  while (S > 1 && off + (size_t)S * partBytes > ws_size) S >>= 1;
  float* part = (float*)alloc((size_t)S * partBytes);
  float* xw1 = part;  // alias; reduceS_k is index-aligned in-place safe
  if (off > ws_size) return;

  zero_k<<<N_NODES / 256, 256, 0, stream>>>(cnt);
  count_deg_k<<<N_EDGES / 256, 256, 0, stream>>>(edst, cnt);
  scan_k<<<1, 1024, 0, stream>>>(cnt, rp, fill, dinv);
  scatter_k<<<N_EDGES / 256, 256, 0, stream>>>(esrc, edst, fill, csr);

  w1split_k<<<dim3(N_NODES / 64, F1 / 32), 256, 0, stream>>>(W1, W1th, W1tl);
  // grid (S, M-blocks of 32): wgid%S == K-slice -> per-XCD B-slice L2 locality
  gemm1_mfma_k<<<dim3(S, N_NODES / 32), 256, 0, stream>>>(x, W1th, W1tl, part, N_NODES / S);
  if (S > 1)
    reduceS_k<<<(N_NODES * F1 / 4) / 256, 256, 0, stream>>>(part, xw1, S);
  agg_k<F1><<<N_NODES, F1, 0, stream>>>(xw1, csr, rp, dinv, b1, h1);

  gemm2_k<<<N_NODES / 16, 256, 0, stream>>>(h1, W2, xw2);
  agg_k<F2><<<N_NODES, F2, 0, stream>>>(xw2, csr, rp, dinv, b2, h2);

  pboth_k<<<N_NODES / 16, 192, 0, stream>>>(h2, Wfc, P);
  final_k<<<(N_PAIRS * 43 + 255) / 256, 256, 0, stream>>>(P, d1, d2, bfc, out);
}

// Round 15
// 251.336 us; speedup vs baseline: 1.1379x; 1.1379x over previous
//
#include <hip/hip_runtime.h>
#include <math.h>
#include <stdint.h>
#include <stddef.h>

#define N_NODES 8192
#define N_EDGES 524288
#define N_PAIRS 262144
#define N_TYPES 86
#define F1 128
#define F2 64

typedef unsigned short ushort_t;
typedef unsigned int uint_t;
typedef __attribute__((ext_vector_type(8))) short bfrag;
typedef __attribute__((ext_vector_type(4))) float ffrag;

typedef __attribute__((address_space(3))) char lds_char;
typedef __attribute__((address_space(1))) const char g_char;

__device__ __forceinline__ void gload16(const void* g, void* l) {
  __builtin_amdgcn_global_load_lds((const g_char*)g, (lds_char*)l, 16, 0, 0);
}

__device__ inline ushort_t f2bf(float f) {
  uint_t u = __float_as_uint(f);
  uint_t r = u + 0x7fffu + ((u >> 16) & 1u);
  return (ushort_t)(r >> 16);
}
__device__ inline float bf2f(ushort_t h) {
  return __uint_as_float(((uint_t)h) << 16);
}

// ---------------- degree / CSR build ----------------

__global__ void zero_k(int* __restrict__ p) {
  p[blockIdx.x * 256 + threadIdx.x] = 0;
}

__global__ void count_deg_k(const int* __restrict__ dst, int* __restrict__ cnt) {
  int e = blockIdx.x * blockDim.x + threadIdx.x;
  if (e < N_EDGES) atomicAdd(&cnt[dst[e]], 1);
}

__global__ void scan_k(const int* __restrict__ cnt, int* __restrict__ rp,
                       int* __restrict__ fill, float* __restrict__ dinv) {
  __shared__ int s[1024];
  int t = threadIdx.x;
  int v[8];
  int sum = 0;
#pragma unroll
  for (int i = 0; i < 8; i++) {
    v[i] = cnt[t * 8 + i];
    dinv[t * 8 + i] = 1.0f / sqrtf((float)(v[i] + 1));
    sum += v[i];
  }
  s[t] = sum;
  __syncthreads();
  for (int off = 1; off < 1024; off <<= 1) {
    int add = (t >= off) ? s[t - off] : 0;
    __syncthreads();
    s[t] += add;
    __syncthreads();
  }
  int excl = s[t] - sum;
#pragma unroll
  for (int i = 0; i < 8; i++) {
    rp[t * 8 + i] = excl;
    fill[t * 8 + i] = excl;
    excl += v[i];
  }
  if (t == 1023) rp[N_NODES] = excl;
}

__global__ void scatter_k(const int* __restrict__ src, const int* __restrict__ dst,
                          int* fill, int* __restrict__ csr) {
  int e = blockIdx.x * blockDim.x + threadIdx.x;
  if (e < N_EDGES) {
    int d = dst[e];
    int pos = atomicAdd(&fill[d], 1);
    csr[pos] = src[e];
  }
}

// ---------------- W1 transpose to bf16: W1t[n][k] = bf16(W1[k][n]) ----------------

__global__ __launch_bounds__(256) void w1t_k(const float* __restrict__ W1,
                                             ushort_t* __restrict__ W1t) {
  __shared__ ushort_t lh[32 * 65];
  int tid = threadIdx.x;
  int k0 = blockIdx.x * 64;
  int n0 = blockIdx.y * 32;
#pragma unroll
  for (int i = 0; i < 8; i++) {
    int c = tid + 256 * i;
    int kr = c >> 5, nc = c & 31;
    lh[nc * 65 + kr] = f2bf(W1[(size_t)(k0 + kr) * F1 + n0 + nc]);
  }
  __syncthreads();
  {
    int c = tid;  // 256 = 32 rows x 8 kc
    int nr = c >> 3, kc = c & 7;
    uint4 u;
    u.x = (uint_t)lh[nr * 65 + kc * 8 + 0] | ((uint_t)lh[nr * 65 + kc * 8 + 1] << 16);
    u.y = (uint_t)lh[nr * 65 + kc * 8 + 2] | ((uint_t)lh[nr * 65 + kc * 8 + 3] << 16);
    u.z = (uint_t)lh[nr * 65 + kc * 8 + 4] | ((uint_t)lh[nr * 65 + kc * 8 + 5] << 16);
    u.w = (uint_t)lh[nr * 65 + kc * 8 + 6] | ((uint_t)lh[nr * 65 + kc * 8 + 7] << 16);
    *(uint4*)(W1t + (size_t)(n0 + nr) * N_NODES + k0 + kc * 8) = u;
  }
}

// ---------------- GEMM1: byte-minimized 2-term split, BM=128 ----------------
// 256 thr (4 waves 2Mx2N), BM=128, BN=128, BK=32, S=8 -> 512 blocks (2/CU).
// 2-term: A split (ah+al), B single bf16 -> B traffic 134MB (vs 537 at R11).
// A-LDS: 128 rows x 128B (H slots 0-3 | L slots 4-7), XOR slot^=(r&7):
//   every 8-lane subgroup spreads across all 8 slot-columns -> conflict-free.
// B: R13 mapping verbatim (64B rows, slot^=(r&3), pre-swizzled global source).
// Schedule = R13 (counted vmcnt 2/0, K-phase rotation, 2 barriers/step).

#define ALDS 0
#define BLDS(b) (16384 + (b) * 8192)

#define SCHED0 __builtin_amdgcn_sched_barrier(0)
#define WAITVM(N)  do { asm volatile("s_waitcnt vmcnt(" #N ")" ::: "memory"); SCHED0; } while (0)
#define WAITVML(N) do { asm volatile("s_waitcnt vmcnt(" #N ") lgkmcnt(0)" ::: "memory"); SCHED0; } while (0)

__global__ __launch_bounds__(256, 2) void gemm1_mfma_k(const float* __restrict__ x,
                                                       const ushort_t* __restrict__ W1t,
                                                       float* __restrict__ part, int kspan) {
  __shared__ __align__(16) char lds[32768];
  int tid = threadIdx.x;
  int wave = tid >> 6, lane = tid & 63;
  int wr = wave >> 1, wc = wave & 1;
  int lrow = lane & 15, kgrp = lane >> 4;
  int m_blk = blockIdx.y * 128;
  int kbase = blockIdx.x * kspan;
  int ktiles = kspan >> 5;  // BK=32
  int s0 = (5 * blockIdx.y + 3 * blockIdx.x) & (ktiles - 1);  // rotation (R13)

  // A: thread covers row ar, 64B half aq of each 128B k-window
  int ar = tid >> 1, aq = tid & 1;
  const float* abase = x + (size_t)(m_blk + ar) * N_NODES + aq * 16;

  // B gload constants (R13 verbatim, H only)
  int bq = wave;
  int b_row = bq * 32 + (lane >> 2);
  int b_kel = ((lane & 3) ^ ((lane >> 2) & 3)) << 3;

  ffrag acc[4][4];
#pragma unroll
  for (int mi = 0; mi < 4; mi++)
#pragma unroll
    for (int ni = 0; ni < 4; ni++) acc[mi][ni] = (ffrag)(0.0f);

  float4 av[4];  // 16 floats = this thread's 64B of the A step

#define LOADA(K0)                                                                    \
  {                                                                                  \
    const float* p_ = abase + (K0);                                                  \
    av[0] = *(const float4*)(p_ + 0);                                                \
    av[1] = *(const float4*)(p_ + 4);                                                \
    av[2] = *(const float4*)(p_ + 8);                                                \
    av[3] = *(const float4*)(p_ + 12);                                               \
  }

#define ISSUE_B(K0, BSEL)                                                            \
  {                                                                                  \
    _Pragma("unroll") for (int i = 0; i < 2; i++) {                                  \
      const ushort_t* gp = W1t + (size_t)(b_row + i * 16) * N_NODES + (K0) + b_kel;  \
      gload16(gp, lds + BLDS(BSEL) + bq * 2048 + i * 1024);                          \
    }                                                                                \
  }

#define STOREA()                                                                     \
  {                                                                                  \
    float f[16];                                                                     \
    f[0]=av[0].x; f[1]=av[0].y; f[2]=av[0].z; f[3]=av[0].w;                          \
    f[4]=av[1].x; f[5]=av[1].y; f[6]=av[1].z; f[7]=av[1].w;                          \
    f[8]=av[2].x; f[9]=av[2].y; f[10]=av[2].z; f[11]=av[2].w;                        \
    f[12]=av[3].x; f[13]=av[3].y; f[14]=av[3].z; f[15]=av[3].w;                      \
    ushort_t h[16], l[16];                                                           \
    _Pragma("unroll") for (int j = 0; j < 16; j++) {                                 \
      h[j] = f2bf(f[j]);                                                             \
      l[j] = f2bf(f[j] - bf2f(h[j]));                                                \
    }                                                                                \
    uint4 H0, H1, L0, L1;                                                            \
    H0.x=(uint_t)h[0]|((uint_t)h[1]<<16);  H0.y=(uint_t)h[2]|((uint_t)h[3]<<16);     \
    H0.z=(uint_t)h[4]|((uint_t)h[5]<<16);  H0.w=(uint_t)h[6]|((uint_t)h[7]<<16);     \
    H1.x=(uint_t)h[8]|((uint_t)h[9]<<16);  H1.y=(uint_t)h[10]|((uint_t)h[11]<<16);   \
    H1.z=(uint_t)h[12]|((uint_t)h[13]<<16); H1.w=(uint_t)h[14]|((uint_t)h[15]<<16);  \
    L0.x=(uint_t)l[0]|((uint_t)l[1]<<16);  L0.y=(uint_t)l[2]|((uint_t)l[3]<<16);     \
    L0.z=(uint_t)l[4]|((uint_t)l[5]<<16);  L0.w=(uint_t)l[6]|((uint_t)l[7]<<16);     \
    L1.x=(uint_t)l[8]|((uint_t)l[9]<<16);  L1.y=(uint_t)l[10]|((uint_t)l[11]<<16);   \
    L1.z=(uint_t)l[12]|((uint_t)l[13]<<16); L1.w=(uint_t)l[14]|((uint_t)l[15]<<16);  \
    uint_t rb = ar * 128, rx = ar & 7;                                               \
    *(uint4*)(lds + ALDS + rb + (((2*aq)   ^ rx) << 4)) = H0;                        \
    *(uint4*)(lds + ALDS + rb + (((2*aq+1) ^ rx) << 4)) = H1;                        \
    *(uint4*)(lds + ALDS + rb + (((4+2*aq) ^ rx) << 4)) = L0;                        \
    *(uint4*)(lds + ALDS + rb + (((5+2*aq) ^ rx) << 4)) = L1;                        \
  }

#define COMPUTE(BSEL)                                                                \
  {                                                                                  \
    bfrag bh[4];                                                                     \
    _Pragma("unroll") for (int ni = 0; ni < 4; ni++) {                               \
      int brow = wc * 64 + ni * 16 + lrow;                                           \
      uint_t boff = brow * 64 + ((kgrp ^ (brow & 3)) << 4);                          \
      bh[ni] = *(const bfrag*)(lds + BLDS(BSEL) + boff);                             \
    }                                                                                \
    _Pragma("unroll") for (int mi = 0; mi < 4; mi++) {                               \
      int arow = wr * 64 + mi * 16 + lrow;                                           \
      uint_t rb = arow * 128, rx = arow & 7;                                         \
      bfrag ah = *(const bfrag*)(lds + ALDS + rb + ((kgrp ^ rx) << 4));              \
      bfrag al = *(const bfrag*)(lds + ALDS + rb + (((4 + kgrp) ^ rx) << 4));        \
      _Pragma("unroll") for (int ni = 0; ni < 4; ni++) {                             \
        acc[mi][ni] = __builtin_amdgcn_mfma_f32_16x16x32_bf16(ah, bh[ni], acc[mi][ni], 0, 0, 0); \
        acc[mi][ni] = __builtin_amdgcn_mfma_f32_16x16x32_bf16(al, bh[ni], acc[mi][ni], 0, 0, 0); \
      }                                                                              \
    }                                                                                \
  }

  // -------- prologue: stage step s0 --------
  LOADA(kbase + (s0 << 5));
  ISSUE_B(kbase + (s0 << 5), 0);
  WAITVM(2);       // A regs landed; 2 B gloads stay in flight
  STOREA();
  WAITVML(0);      // B0 in LDS + A ds_writes visible
  __builtin_amdgcn_s_barrier();
  SCHED0;

  int sp = s0;
  for (int s = 0; s < ktiles; ++s) {
    int more = (s + 1 < ktiles);
    int spn = sp + 1; if (spn == ktiles) spn = 0;
    if (more) {
      int k0n = kbase + (spn << 5);
      LOADA(k0n);                 // 4 vm (oldest)
      SCHED0;
      ISSUE_B(k0n, (s + 1) & 1);  // 2 vm (newest)
      SCHED0;
    }
    __builtin_amdgcn_s_setprio(1);
    COMPUTE(s & 1);
    __builtin_amdgcn_s_setprio(0);
    __builtin_amdgcn_s_barrier();  // all waves done reading A-LDS + B(s)
    SCHED0;
    if (more) {
      WAITVM(2);   // A regs landed (B(s+1) stays in flight)
      STOREA();
      WAITVML(0);  // B(s+1) landed + A writes drained
      __builtin_amdgcn_s_barrier();
      SCHED0;
    }
    sp = spn;
  }

  // -------- epilogue: C[row=(lane>>4)*4+r][col=lane&15] per 16x16 frag --------
  float* outp = part + (size_t)blockIdx.x * (N_NODES * F1);
#pragma unroll
  for (int mi = 0; mi < 4; mi++) {
#pragma unroll
    for (int ni = 0; ni < 4; ni++) {
      int col = wc * 64 + ni * 16 + lrow;
#pragma unroll
      for (int r = 0; r < 4; r++) {
        int row = m_blk + wr * 64 + mi * 16 + kgrp * 4 + r;
        outp[(size_t)row * F1 + col] = acc[mi][ni][r];
      }
    }
  }
#undef LOADA
#undef ISSUE_B
#undef STOREA
#undef COMPUTE
}

// in-place safe: each thread reads all S parts at its index, then writes part[0].
__global__ void reduceS_k(const float* __restrict__ part, float* __restrict__ xw1, int S) {
  int i = blockIdx.x * blockDim.x + threadIdx.x;
  float4 a = ((const float4*)part)[i];
  for (int s = 1; s < S; s++) {
    float4 b = ((const float4*)(part + (size_t)s * N_NODES * F1))[i];
    a.x += b.x; a.y += b.y; a.z += b.z; a.w += b.w;
  }
  ((float4*)xw1)[i] = a;
}

// ---------------- aggregation (gather over CSR) + bias + relu ----------------

template <int F>
__global__ void agg_k(const float* __restrict__ xw, const int* __restrict__ csr,
                      const int* __restrict__ rp, const float* __restrict__ dinv,
                      const float* __restrict__ bias, float* __restrict__ hout) {
  int node = blockIdx.x;
  int f = threadIdx.x;
  __shared__ int sidx[F];
  __shared__ float sdv[F];
  int beg = rp[node], end = rp[node + 1];
  float acc = 0.f;
  for (int base = beg; base < end; base += F) {
    int n = end - base;
    if (n > F) n = F;
    __syncthreads();
    if (f < n) {
      int s = csr[base + f];
      sidx[f] = s;
      sdv[f] = dinv[s];
    }
    __syncthreads();
    for (int i = 0; i < n; i++) acc += xw[(size_t)sidx[i] * F + f] * sdv[i];
  }
  float dv = dinv[node];
  float v = (acc + xw[(size_t)node * F + f] * dv) * dv + bias[f];
  hout[(size_t)node * F + f] = v > 0.f ? v : 0.f;
}

// ---------------- GEMM2: h1[8192,128] @ W2[128,64] ----------------

__global__ __launch_bounds__(256) void gemm2_k(const float* __restrict__ h1,
                                               const float* __restrict__ W2,
                                               float* __restrict__ xw2) {
  __shared__ float W2s[F1 * F2];
  __shared__ float As[16 * F1];
  int tid = threadIdx.x;
  int r0 = blockIdx.x * 16;
#pragma unroll
  for (int j = 0; j < 8; j++)
    ((float4*)W2s)[tid + 256 * j] = ((const float4*)W2)[tid + 256 * j];
#pragma unroll
  for (int j = 0; j < 2; j++)
    ((float4*)As)[tid + 256 * j] = ((const float4*)(h1 + (size_t)r0 * F1))[tid + 256 * j];
  __syncthreads();
  int r = tid >> 4, c4 = tid & 15;
  float4 acc = make_float4(0.f, 0.f, 0.f, 0.f);
#pragma unroll 8
  for (int k = 0; k < F1; k++) {
    float a = As[r * F1 + k];
    float4 bv = *(float4*)&W2s[k * F2 + 4 * c4];
    acc.x += a * bv.x; acc.y += a * bv.y; acc.z += a * bv.z; acc.w += a * bv.w;
  }
  *(float4*)&xw2[(size_t)(r0 + r) * F2 + 4 * c4] = acc;
}

// ---------------- P tables: P[i][0:86]=h2[i]@Wfc[:64], P[i][86:172]=h2[i]@Wfc[64:] ----------------

__global__ void pboth_k(const float* __restrict__ h2, const float* __restrict__ Wfc,
                        float* __restrict__ P) {
  __shared__ float hs[64 * 16];
  int tid = threadIdx.x;  // 192
  int r0 = blockIdx.x * 16;
  for (int idx = tid; idx < 256; idx += 192) {
    int row = idx >> 4, k4 = idx & 15;
    float4 h = *(const float4*)&h2[(size_t)(r0 + row) * F2 + 4 * k4];
    hs[(4 * k4 + 0) * 16 + row] = h.x;
    hs[(4 * k4 + 1) * 16 + row] = h.y;
    hs[(4 * k4 + 2) * 16 + row] = h.z;
    hs[(4 * k4 + 3) * 16 + row] = h.w;
  }
  __syncthreads();
  if (tid < 172) {
    int half = tid < 86 ? 0 : 1;
    int j = tid - 86 * half;
    const float* wp = Wfc + (size_t)(64 * half) * N_TYPES + j;
    float acc[16];
#pragma unroll
    for (int r = 0; r < 16; r++) acc[r] = 0.f;
    for (int k = 0; k < 64; k++) {
      float w = wp[(size_t)k * N_TYPES];
      const float* hk = &hs[k * 16];
#pragma unroll
      for (int r = 0; r < 16; r++) acc[r] += hk[r] * w;
    }
#pragma unroll
    for (int r = 0; r < 16; r++) P[(size_t)(r0 + r) * 172 + tid] = acc[r];
  }
}

// ---------------- final: out[p][t] = sigmoid(P1[d1[p]][t] + P2[d2[p]][t] + bfc[t]) ----------------

__global__ void final_k(const float* __restrict__ P, const int* __restrict__ d1,
                        const int* __restrict__ d2, const float* __restrict__ bfc,
                        float* __restrict__ out) {
  int gid = blockIdx.x * blockDim.x + threadIdx.x;
  if (gid >= N_PAIRS * 43) return;
  int p = gid / 43;
  int j = gid - p * 43;
  int a = d1[p], b = d2[p];
  float2 v1 = *(const float2*)&P[(size_t)a * 172 + 2 * j];
  float2 v2 = *(const float2*)&P[(size_t)b * 172 + 86 + 2 * j];
  float2 bb = *(const float2*)&bfc[2 * j];
  float z0 = v1.x + v2.x + bb.x;
  float z1 = v1.y + v2.y + bb.y;
  float2 o;
  o.x = 1.0f / (1.0f + expf(-z0));
  o.y = 1.0f / (1.0f + expf(-z1));
  *(float2*)&out[(size_t)p * 86 + 2 * j] = o;
}

// ---------------- launch ----------------

extern "C" void kernel_launch(void* const* d_in, const int* in_sizes, int n_in,
                              void* d_out, int out_size, void* d_ws, size_t ws_size,
                              hipStream_t stream) {
  const float* x   = (const float*)d_in[0];
  const int*   ei  = (const int*)d_in[1];
  const int*   d1  = (const int*)d_in[2];
  const int*   d2  = (const int*)d_in[3];
  const float* W1  = (const float*)d_in[4];
  const float* b1  = (const float*)d_in[5];
  const float* W2  = (const float*)d_in[6];
  const float* b2  = (const float*)d_in[7];
  const float* Wfc = (const float*)d_in[8];
  const float* bfc = (const float*)d_in[9];
  float* out = (float*)d_out;

  const int* esrc = ei;
  const int* edst = ei + N_EDGES;

  char* w = (char*)d_ws;
  size_t off = 0;
  auto alloc = [&](size_t bytes) -> char* {
    char* p = w + off;
    off += (bytes + 255) & ~(size_t)255;
    return p;
  };
  int*      cnt  = (int*)alloc((size_t)N_NODES * 4);
  float*    dinv = (float*)alloc((size_t)N_NODES * 4);
  int*      rp   = (int*)alloc((size_t)(N_NODES + 1) * 4);
  int*      fill = (int*)alloc((size_t)N_NODES * 4);
  int*      csr  = (int*)alloc((size_t)N_EDGES * 4);
  ushort_t* W1t  = (ushort_t*)alloc((size_t)N_NODES * F1 * 2);
  float*    h1   = (float*)alloc((size_t)N_NODES * F1 * 4);
  float*    xw2  = (float*)alloc((size_t)N_NODES * F2 * 4);
  float*    h2   = (float*)alloc((size_t)N_NODES * F2 * 4);
  float*    P    = (float*)alloc((size_t)N_NODES * 172 * 4);

  size_t partBytes = (size_t)N_NODES * F1 * 4;  // 4MB per split
  int S = 8;
  while (S > 1 && off + (size_t)S * partBytes > ws_size) S >>= 1;
  float* part = (float*)alloc((size_t)S * partBytes);
  float* xw1 = part;  // alias; reduceS_k is index-aligned in-place safe
  if (off > ws_size) return;

  zero_k<<<N_NODES / 256, 256, 0, stream>>>(cnt);
  count_deg_k<<<N_EDGES / 256, 256, 0, stream>>>(edst, cnt);
  scan_k<<<1, 1024, 0, stream>>>(cnt, rp, fill, dinv);
  scatter_k<<<N_EDGES / 256, 256, 0, stream>>>(esrc, edst, fill, csr);

  w1t_k<<<dim3(N_NODES / 64, F1 / 32), 256, 0, stream>>>(W1, W1t);
  // grid (S, M-blocks of 128): wgid%S == K-slice -> per-XCD B-slice L2 locality
  gemm1_mfma_k<<<dim3(S, N_NODES / 128), 256, 0, stream>>>(x, W1t, part, N_NODES / S);
  if (S > 1)
    reduceS_k<<<(N_NODES * F1 / 4) / 256, 256, 0, stream>>>(part, xw1, S);
  agg_k<F1><<<N_NODES, F1, 0, stream>>>(xw1, csr, rp, dinv, b1, h1);

  gemm2_k<<<N_NODES / 16, 256, 0, stream>>>(h1, W2, xw2);
  agg_k<F2><<<N_NODES, F2, 0, stream>>>(xw2, csr, rp, dinv, b2, h2);

  pboth_k<<<N_NODES / 16, 192, 0, stream>>>(h2, Wfc, P);
  final_k<<<(N_PAIRS * 43 + 255) / 256, 256, 0, stream>>>(P, d1, d2, bfc, out);
}